// Round 5
// baseline (213.716 us; speedup 1.0000x reference)
//
#include <hip/hip_runtime.h>
#include <hip/hip_fp16.h>

#define S_DIM 512
#define B_DIM 256
#define H_DIM 500
#define HP    512
#define M_DIM (S_DIM * B_DIM)     // 131072

typedef _Float16 half8_t __attribute__((ext_vector_type(8)));
typedef _Float16 half4_t __attribute__((ext_vector_type(4)));
typedef float    f32x4  __attribute__((ext_vector_type(4)));

// workspace layout (bytes)
#define WS_W2I 0                       // fp16 W2img [16][512][4][8] = 512 KB (LDS-image order)
#define WS_AT  (512 * 1024)            // fp32 At[h][b] [512][256]   = 512 KB
#define WS_VP  (1024 * 1024)           // fp32 [512]                 =   2 KB
#define WS_SC  (1024 * 1024 + 4096)    // fp32 sct[b][s] [256][512]  = 512 KB

__device__ __forceinline__ void gld_lds16(const void* g, void* l) {
    __builtin_amdgcn_global_load_lds(
        (const __attribute__((address_space(1))) unsigned int*)g,
        (__attribute__((address_space(3))) unsigned int*)l, 16, 0, 0);
}

template<int N> __device__ __forceinline__ void vwait();
template<> __device__ __forceinline__ void vwait<0>() { asm volatile("s_waitcnt vmcnt(0)" ::: "memory"); }
template<> __device__ __forceinline__ void vwait<1>() { asm volatile("s_waitcnt vmcnt(1)" ::: "memory"); }

// ---- prep: W2 -> fp16 in LDS-image order: plane ks, slot = n*4 + cL, 8 halves.
// Element chunk ce stored at cL = ce ^ ((n>>1)&3)  (verified 0-conflict swizzle).
__global__ void prep_w2_v(const float* __restrict__ W, const float* __restrict__ v,
                          _Float16* __restrict__ W2img, float* __restrict__ vp) {
    int idx = blockIdx.x * blockDim.x + threadIdx.x;   // 0..131071
#pragma unroll
    for (int r = 0; r < 2; ++r) {
        int e = idx + r * 131072;                      // 0..262143
        int n = e >> 9, k = e & 511;
        float val = (n < H_DIM && k < H_DIM) ? W[n * 1000 + 500 + k] : 0.0f;
        int ks = k >> 5, ce = (k >> 3) & 3, u = k & 7;
        int cL = ce ^ ((n >> 1) & 3);
        W2img[((ks * 512 + n) * 4 + cL) * 8 + u] = (_Float16)val;
    }
    if (idx < HP) vp[idx] = (idx < H_DIM) ? v[idx] : 0.0f;
}

// ---- prep: At[h][b] = b_attn[h] + hidden[b,:] . W1[h,:]  (exact fp32, transposed) ----
__global__ void prep_A(const float* __restrict__ hidden, const float* __restrict__ W,
                       const float* __restrict__ b_attn, float* __restrict__ At) {
    int b = blockIdx.x;
    int t = threadIdx.x;               // 0..511 = h
    __shared__ float hs[HP];
    hs[t] = (t < H_DIM) ? hidden[b * H_DIM + t] : 0.0f;
    __syncthreads();
    float acc = 0.0f;
    if (t < H_DIM) {
        acc = b_attn[t];
        const float4* wr = (const float4*)(W + t * 1000);
        const float4* hr = (const float4*)hs;
#pragma unroll 5
        for (int i = 0; i < 125; ++i) {
            float4 w4 = wr[i], h4 = hr[i];
            acc += w4.x * h4.x + w4.y * h4.y + w4.z * h4.z + w4.w * h4.w;
        }
    }
    At[t * B_DIM + b] = acc;
}

// ---- main: BM=64 x full N=512, 512 thr = 8 waves, wave-tile 64x64 (acc[4][4]).
// Deep pipeline: B gld_lds 1 step ahead (counted vmcnt(1)), A global loads 2 steps
// ahead (held in flight across the raw s_barrier), cvt+ds_write after MFMAs.
__launch_bounds__(512, 4)
__global__ void fused_attn_gemm(const float* __restrict__ enc,
                                const _Float16* __restrict__ W2img,
                                const float* __restrict__ At,
                                const float* __restrict__ vp,
                                float* __restrict__ sct) {
    __shared__ _Float16 As[2][64][32];    //  8 KB
    __shared__ _Float16 Bs[2][512][32];   // 64 KB
    __shared__ float    red[8][64];       //  2 KB

    const int tid  = threadIdx.x;
    const int lane = tid & 63;
    const int wid  = tid >> 6;            // 0..7 (wave's 64-col slice)
    const int l15  = lane & 15;
    const int lq   = lane >> 4;           // 0..3

    const int mblk  = blockIdx.x;         // 0..2047
    const int m0    = mblk * 64;
    const int s_idx = mblk >> 2;
    const int bloc  = (mblk & 3) * 64;

    // A staging: thread -> (row r = tid>>3, j = tid&7); one f32x4 per k-slice.
    const int r = tid >> 3;               // 0..63
    const int j = tid & 7;                // 0..7 (k-subchunk of 4)
    const float* gA  = enc + (size_t)(m0 + r) * H_DIM + j * 4;
    const float* gAt = enc + (size_t)(m0 + r) * H_DIM + 480 + (j < 4 ? j : 4) * 4; // clamped tail
    const bool   jz  = (j >= 5);          // tail elements k>=500 -> zero
    // swizzled A write slot: chunk c = j>>1 -> c^( (r>>1)&3 ), half-offset +(j&1)*4
    const int aoff = ((j >> 1) ^ ((r >> 1) & 3)) * 8 + (j & 1) * 4;

    // swizzled fragment-read chunk (constant per lane)
    const int rch = (lq ^ ((l15 >> 1) & 3)) * 8;

    _Float16* BsLin0 = (_Float16*)&Bs[0][0][0];
    _Float16* BsLin1 = (_Float16*)&Bs[1][0][0];

    f32x4 acc[4][4];
#pragma unroll
    for (int a = 0; a < 4; ++a)
#pragma unroll
        for (int b = 0; b < 4; ++b) acc[a][b] = 0;

    auto ldA = [&](int slice) -> f32x4 {
        return (slice == 15) ? *(const f32x4*)gAt : *(const f32x4*)(gA + slice * 32);
    };
    auto wrA = [&](int buf, f32x4 v4, bool tail) {
        half4_t h;
#pragma unroll
        for (int u = 0; u < 4; ++u) h[u] = (tail && jz) ? (_Float16)0.0f : (_Float16)v4[u];
        *(half4_t*)&As[buf][r][aoff] = h;
    };
    auto stB = [&](int buf, int ksrc) {
        const _Float16* gbase = W2img + (size_t)ksrc * 16384;
        _Float16* dl = buf ? BsLin1 : BsLin0;
#pragma unroll
        for (int i = 0; i < 4; ++i) {
            int slotb = wid * 256 + i * 64;
            gld_lds16(gbase + (size_t)(slotb + lane) * 8, dl + slotb * 8);
        }
    };
    auto compute = [&](int cur) {
        half8_t af[4];
#pragma unroll
        for (int mf = 0; mf < 4; ++mf)
            af[mf] = *(const half8_t*)&As[cur][mf * 16 + l15][rch];
#pragma unroll
        for (int nf = 0; nf < 4; ++nf) {
            half8_t bq = *(const half8_t*)&Bs[cur][wid * 64 + nf * 16 + l15][rch];
#pragma unroll
            for (int mf = 0; mf < 4; ++mf)
                acc[mf][nf] = __builtin_amdgcn_mfma_f32_16x16x32_f16(af[mf], bq, acc[mf][nf], 0, 0, 0);
        }
    };

    f32x4 r0, r1;
    // prologue: A(0) load, B(0) stage, A(1) load, write As[0]
    {
        f32x4 rA = ldA(0);                 // vm: A0
        stB(0, 0);                         // vm: A0,B0x4
        r1 = ldA(1);                       // vm: A0,B0x4,A1
        wrA(0, rA, false);                 // compiler drains A0 (vmcnt(5)), leaves B0+A1
    }

#define KSTEP(KS, CUR, RN, RX)                                            \
    {                                                                     \
        if ((KS) >= 14) vwait<0>(); else vwait<1>();                      \
        asm volatile("s_waitcnt lgkmcnt(0)" ::: "memory");                \
        __builtin_amdgcn_sched_barrier(0);                                \
        __builtin_amdgcn_s_barrier();                                     \
        __builtin_amdgcn_sched_barrier(0);                                \
        if ((KS) + 1 < 16) stB((CUR) ^ 1, (KS) + 1);                      \
        __builtin_amdgcn_sched_barrier(0);                                \
        if ((KS) + 2 < 16) RX = ldA((KS) + 2);                            \
        compute(CUR);                                                     \
        if ((KS) + 1 < 16) wrA((CUR) ^ 1, RN, (KS) + 1 == 15);            \
    }

    KSTEP(0, 0, r1, r0)   KSTEP(1, 1, r0, r1)
    KSTEP(2, 0, r1, r0)   KSTEP(3, 1, r0, r1)
    KSTEP(4, 0, r1, r0)   KSTEP(5, 1, r0, r1)
    KSTEP(6, 0, r1, r0)   KSTEP(7, 1, r0, r1)
    KSTEP(8, 0, r1, r0)   KSTEP(9, 1, r0, r1)
    KSTEP(10, 0, r1, r0)  KSTEP(11, 1, r0, r1)
    KSTEP(12, 0, r1, r0)  KSTEP(13, 1, r0, r1)
    KSTEP(14, 0, r1, r0)  KSTEP(15, 1, r0, r1)
#undef KSTEP

    // ---- epilogue: scores = sum_h v[h] * tanh(At + E) ----
    float vpv[4];
#pragma unroll
    for (int nf = 0; nf < 4; ++nf) vpv[nf] = vp[wid * 64 + nf * 16 + l15];

    float pj[4][4];
#pragma unroll
    for (int mf = 0; mf < 4; ++mf)
#pragma unroll
        for (int jj = 0; jj < 4; ++jj) pj[mf][jj] = 0.0f;

#pragma unroll
    for (int mf = 0; mf < 4; ++mf) {
#pragma unroll
        for (int nf = 0; nf < 4; ++nf) {
            int h = wid * 64 + nf * 16 + l15;
            f32x4 av = *(const f32x4*)(At + h * B_DIM + bloc + mf * 16 + lq * 4);
#pragma unroll
            for (int jj = 0; jj < 4; ++jj) {
                float x  = acc[mf][nf][jj] + av[jj];
                float xc = fminf(fmaxf(x, -9.0f), 9.0f);
                float e  = __expf(2.0f * xc);
                float th = (e - 1.0f) / (e + 1.0f);
                pj[mf][jj] += vpv[nf] * th;
            }
        }
    }

#pragma unroll
    for (int mf = 0; mf < 4; ++mf)
#pragma unroll
        for (int jj = 0; jj < 4; ++jj) {
            float s = pj[mf][jj];
            s += __shfl_xor(s, 1); s += __shfl_xor(s, 2);
            s += __shfl_xor(s, 4); s += __shfl_xor(s, 8);
            if (l15 == 0) red[wid][mf * 16 + lq * 4 + jj] = s;
        }
    __syncthreads();
    if (tid < 64) {
        float p = 0.0f;
#pragma unroll
        for (int w = 0; w < 8; ++w) p += red[w][tid];
        sct[(size_t)(bloc + tid) * S_DIM + s_idx] = p;
    }
}

// ---- softmax over S per b; out[b][0][s] ----
__global__ void softmax_rows(const float* __restrict__ sct, float* __restrict__ out) {
    int b = blockIdx.x;
    int t = threadIdx.x;                  // 512 threads, one s each
    int lane = t & 63, w = t >> 6;
    float v = sct[(size_t)b * S_DIM + t];
    float m = v;
#pragma unroll
    for (int off = 1; off < 64; off <<= 1) m = fmaxf(m, __shfl_xor(m, off));
    __shared__ float sm[8], ss[8];
    if (lane == 0) sm[w] = m;
    __syncthreads();
    m = sm[0];
#pragma unroll
    for (int i = 1; i < 8; ++i) m = fmaxf(m, sm[i]);
    float e = __expf(v - m);
    float s = e;
#pragma unroll
    for (int off = 1; off < 64; off <<= 1) s += __shfl_xor(s, off);
    if (lane == 0) ss[w] = s;
    __syncthreads();
    s = ss[0];
#pragma unroll
    for (int i = 1; i < 8; ++i) s += ss[i];
    out[(size_t)b * S_DIM + t] = e / s;
}

extern "C" void kernel_launch(void* const* d_in, const int* in_sizes, int n_in,
                              void* d_out, int out_size, void* d_ws, size_t ws_size,
                              hipStream_t stream) {
    const float* hidden = (const float*)d_in[0];
    const float* enc    = (const float*)d_in[1];
    const float* W      = (const float*)d_in[2];
    const float* b_attn = (const float*)d_in[3];
    const float* v      = (const float*)d_in[4];
    float* out = (float*)d_out;

    char* ws = (char*)d_ws;
    _Float16* W2i = (_Float16*)(ws + WS_W2I);
    float*    At  = (float*)(ws + WS_AT);
    float*    vp  = (float*)(ws + WS_VP);
    float*    sct = (float*)(ws + WS_SC);

    prep_w2_v<<<512, 256, 0, stream>>>(W, v, W2i, vp);
    prep_A<<<256, 512, 0, stream>>>(hidden, W, b_attn, At);
    fused_attn_gemm<<<2048, 512, 0, stream>>>(enc, W2i, At, vp, sct);
    softmax_rows<<<256, 512, 0, stream>>>(sct, out);
}